// Round 4
// baseline (741.248 us; speedup 1.0000x reference)
//
#include <hip/hip_runtime.h>
#include <cstddef>

#define THRESH 0.1f

constexpr int Bn = 8, C = 256, H = 128, W = 128;
constexpr int HW = H * W;
constexpr size_t CHW = (size_t)C * HW;
constexpr int WSZ = 9 * 256 * 256;          // elements per transformed weight
constexpr int WT_ELEM = 18432;              // weight tile elements per cib (36864 B)
constexpr int ACT_ELEM = 4 * 132 * 32;      // activation tile elements (33792 B)
constexpr int BUF_ELEM = WT_ELEM + ACT_ELEM;         // 35328 elem = 70656 B
constexpr int SA_BYTES = 2 * BUF_ELEM * 2;           // 141312 B (double-buffered)

typedef __attribute__((ext_vector_type(8))) short short8;   // 8 bf16
typedef __attribute__((ext_vector_type(4))) float f32x4;

__device__ __forceinline__ float bf2f(ushort u) {
    union { unsigned u; float f; } v; v.u = ((unsigned)u) << 16; return v.f;
}
__device__ __forceinline__ ushort f2bf(float f) {
    union { float f; unsigned u; } v; v.f = f;
    unsigned r = v.u + 0x7FFF + ((v.u >> 16) & 1);   // RNE
    return (ushort)(r >> 16);
}
__device__ __forceinline__ float pm(float x, float a) {
    float t = (x >= 0.f) ? x : a * x;                 // prelu
    return (fabsf(t) >= THRESH) ? t : 0.f;            // NaNConv input mask
}

// async global->LDS, 16 B per lane; LDS side is wave-uniform base + lane*16
__device__ __forceinline__ void load_lds16(const void* g, void* l) {
    __builtin_amdgcn_global_load_lds(
        (const __attribute__((address_space(1))) unsigned int*)g,
        (__attribute__((address_space(3))) unsigned int*)l, 16, 0, 0);
}

// ---------------------------------------------------------------------------
// Weight transform: fp32 [co][ci][3][3] -> bf16 fragment-major
// [co>>6][ci>>5][tap][mfrag][lane64][8]   (lane = (co&15) + 16*((ci>>3)&3))
__global__ void wtrans_kernel(const float* __restrict__ w1,
                              const float* __restrict__ w2,
                              const float* __restrict__ w3,
                              ushort* __restrict__ Wtf)
{
    const float* src = (blockIdx.z == 0) ? w1 : (blockIdx.z == 1) ? w2 : w3;
    ushort* dst = Wtf + (size_t)blockIdx.z * WSZ;
    int idx = blockIdx.x * 256 + threadIdx.x;   // 0..65535 = co*256+ci
    int co = idx >> 8, ci = idx & 255;
    int cb  = co >> 6;
    int m   = (co >> 4) & 3;
    int l15 = co & 15;
    int cib = ci >> 5;
    int l4  = (ci >> 3) & 3;
    int j   = ci & 7;
    int lane = l15 + 16 * l4;
    for (int t = 0; t < 9; ++t) {
        float v = src[((size_t)co * 256 + ci) * 9 + t];
        size_t o = ((((size_t)cb * 8 + cib) * 9 + t) * 4 + m) * 512 + lane * 8 + j;
        dst[o] = f2bf(v);
    }
}

// ---------------------------------------------------------------------------
// x (fp32 NCHW) -> Xt (bf16 NHWC) with pm applied.  grid (4, 128, 8)
__global__ __launch_bounds__(256) void xt1_kernel(const float* __restrict__ x,
                                                  const float* __restrict__ pa,
                                                  ushort* __restrict__ Xt)
{
    __shared__ float sl[64][133];
    int tid = threadIdx.x;
    int ci0 = blockIdx.x * 64, h = blockIdx.y, b = blockIdx.z;
    float a = pa[0];
    int wcol = tid & 127, chalf = tid >> 7;
    const float* xb = x + (size_t)b * CHW + (size_t)ci0 * HW + h * W;
    for (int r = 0; r < 32; ++r) {
        int ci = r * 2 + chalf;
        sl[ci][wcol] = pm(xb[(size_t)ci * HW + wcol], a);
    }
    __syncthreads();
    ushort* dst = Xt + ((size_t)(b * H + h)) * W * C + ci0;
    for (int r = 0; r < 4; ++r) {
        int c = r * 256 + tid;
        int wc = c >> 3, cic = c & 7;
        unsigned p0 = f2bf(sl[cic*8+0][wc]) | ((unsigned)f2bf(sl[cic*8+1][wc]) << 16);
        unsigned p1 = f2bf(sl[cic*8+2][wc]) | ((unsigned)f2bf(sl[cic*8+3][wc]) << 16);
        unsigned p2 = f2bf(sl[cic*8+4][wc]) | ((unsigned)f2bf(sl[cic*8+5][wc]) << 16);
        unsigned p3 = f2bf(sl[cic*8+6][wc]) | ((unsigned)f2bf(sl[cic*8+7][wc]) << 16);
        uint4 v = {p0, p1, p2, p3};
        *(uint4*)(dst + (size_t)wc * C + cic * 8) = v;
    }
}

// ---------------------------------------------------------------------------
// Implicit-GEMM 3x3 conv, bf16 MFMA, fused epilogue, 2-phase LDS pipeline.
// Block: 512 threads / 8 waves; GEMM tile 64 co x (2 h-rows x 128 w).
// Wave wv: hrow = wv>>2, quarter q = wv&3 -> 32-pixel strip; frags 4m x 2n.
// LDS: double-buffered [weights WT_ELEM | activations ACT_ELEM] x 2.
//   Compute phase is PURE ds_read+MFMA (no global loads) -> safe to pipeline:
//   issue stage(cib+1) into buf^1 BEFORE compute(cib); one explicit
//   vmcnt(0) + raw s_barrier per tile (loads had whole compute to land).
// Activations: sact[r4][wi132][chunk4][8ci], chunk XOR-swizzled by
//   ((row>>1)&3) via pre-swizzled GLOBAL source (LDS dest stays linear).
// grid 1D 2048, XCD-chunked swizzle: each XCD owns contiguous by-range, cb fastest.
//
// MODE 0: out fp32 NCHW = acc + bias                      (conv3)
// MODE 1: m = max(x_f32, acc+bias); xmax(NHWC)=m; XtOut=pm(m)   (conv1 + maxt1)
// MODE 2: m = max(acc+bias, xmax(NHWC)); XtOut=pm(m)            (conv2 + maxt2)
template <int MODE>
__global__ __launch_bounds__(512, 1) void conv_kernel(
    const ushort* __restrict__ Xt, const ushort* __restrict__ Wtf,
    const float* __restrict__ bias, const float* __restrict__ pa,
    const float* __restrict__ xf,      // MODE 1: original x, fp32 NCHW
    ushort* __restrict__ xmax,         // MODE 1: write NHWC; MODE 2: read NHWC
    ushort* __restrict__ XtOut,        // MODE 1/2: next-layer input, NHWC pm'd
    float* __restrict__ out)           // MODE 0
{
    extern __shared__ __align__(16) ushort sa[];   // 2 x [WT_ELEM | ACT_ELEM]

    const int tid = threadIdx.x, lane = tid & 63, wv = tid >> 6;
    // XCD-chunked bijective swizzle (2048 % 8 == 0)
    const int orig = blockIdx.x;
    const int vid = (orig & 7) * 256 + (orig >> 3);
    const int cb = vid & 3, by = vid >> 2;
    const int co0 = cb * 64;
    const int b = by >> 6, h0 = (by & 63) * 2;
    const int l15 = lane & 15, l4 = lane >> 4;
    const int hrow = wv >> 2, q = wv & 3;

    // zero both activation regions once; OOB rows / halo chunks never overwritten
    {
        uint4 z = {0, 0, 0, 0};
        for (int i = tid; i < 2 * (ACT_ELEM / 8); i += 512) {
            int buf = (i >= ACT_ELEM / 8);
            int off = buf ? (i - ACT_ELEM / 8) : i;
            *((uint4*)(sa + buf * BUF_ELEM + WT_ELEM) + off) = z;
        }
    }
    __syncthreads();

    f32x4 acc[4][2];
    const f32x4 z4 = {0.f, 0.f, 0.f, 0.f};
#pragma unroll
    for (int m = 0; m < 4; ++m)
#pragma unroll
        for (int n = 0; n < 2; ++n) acc[m][n] = z4;

    const ushort* xb = Xt + (size_t)b * H * W * C;
    // act staging: row sr = wv&3 (hh = h0-1+sr), w-half = wv>>2 (segs half*4..+3)
    const int sr = wv & 3, shalf = wv >> 2;
    const int shh = h0 - 1 + sr;
    const bool svalid = (unsigned)shh < 128u;
    const ushort* sgbase = xb + (size_t)shh * W * C;
    const int lchunk = lane >> 2, lsub = lane & 3;
    const ushort* wtb = Wtf + (size_t)cb * 8 * WT_ELEM;

    auto stage = [&](int buf, int cib) {
        const int ci0 = cib * 32;
        // weights: 2304 16B-chunks in 36 groups of 64; wave takes g = wv+8k
        const ushort* wsrc = wtb + (size_t)cib * WT_ELEM;
        ushort* swb = sa + buf * BUF_ELEM;
        for (int g = wv; g < 36; g += 8)
            load_lds16(wsrc + (size_t)(g * 64 + lane) * 8, swb + (size_t)g * 512);
        // activations: 4 segs per wave
        if (svalid) {
            ushort* slb = swb + WT_ELEM + (sr * 132 + 1) * 32;
#pragma unroll
            for (int s = 0; s < 4; ++s) {
                int seg = shalf * 4 + s;
                int ww = seg * 16 + lchunk;   // 0..127
                int key = ((sr * 132 + 1 + ww) >> 1) & 3;
                const void* gp = sgbase + (size_t)ww * C + ci0 + ((lsub ^ key) << 3);
                load_lds16(gp, slb + seg * 512);
            }
        }
    };

    // prologue: tile 0 -> buf 0
    stage(0, 0);
    asm volatile("s_waitcnt vmcnt(0)" ::: "memory");
    __builtin_amdgcn_s_barrier();
    __builtin_amdgcn_sched_barrier(0);

    for (int cib = 0; cib < 8; ++cib) {
        const int cur = cib & 1;
        // issue next tile's loads; they fly while we compute from buf[cur]
        if (cib < 7) stage(cur ^ 1, cib + 1);
        __builtin_amdgcn_sched_barrier(0);

        const ushort* swc = sa + cur * BUF_ELEM;
        const ushort* sact = swc + WT_ELEM;
#pragma unroll
        for (int ky = 0; ky < 3; ++ky) {
            const int r = hrow + ky;
#pragma unroll
            for (int kx = 0; kx < 3; ++kx) {
                const int t = ky * 3 + kx;
                short8 af[4], bfv[2];
#pragma unroll
                for (int m = 0; m < 4; ++m)
                    af[m] = *(const short8*)(swc + (size_t)(t * 4 + m) * 512 + lane * 8);
#pragma unroll
                for (int n = 0; n < 2; ++n) {
                    int wi = q * 32 + n * 16 + l15 + kx;          // 0..129
                    int row = r * 132 + wi;
                    int key = (row >> 1) & 3;                      // matches write side
                    bfv[n] = *(const short8*)(sact + row * 32 + ((l4 ^ key) << 3));
                }
#pragma unroll
                for (int m = 0; m < 4; ++m)
#pragma unroll
                    for (int n = 0; n < 2; ++n)
                        acc[m][n] = __builtin_amdgcn_mfma_f32_16x16x32_bf16(
                            af[m], bfv[n], acc[m][n], 0, 0, 0);
            }
        }
        // release buffers: this wave's ds_reads are consumed (compiler lgkm
        // waits before MFMA); drain the prefetch we issued (it had the whole
        // compute phase to land), then raw barrier - no compiler full-drain.
        __builtin_amdgcn_sched_barrier(0);
        asm volatile("s_waitcnt vmcnt(0)" ::: "memory");
        __builtin_amdgcn_s_barrier();
        __builtin_amdgcn_sched_barrier(0);
    }

    // epilogue: D row = l4*4+rr (co), col = l15 (w)
    const int h = h0 + hrow;
    const float ap = (MODE != 0) ? pa[0] : 0.f;
#pragma unroll
    for (int m = 0; m < 4; ++m) {
        const int cobase = co0 + m * 16 + l4 * 4;
        const f32x4 bv = *(const f32x4*)(bias + cobase);
#pragma unroll
        for (int n = 0; n < 2; ++n) {
            const int wc = q * 32 + n * 16 + l15;
            if constexpr (MODE == 0) {
#pragma unroll
                for (int rr = 0; rr < 4; ++rr)
                    out[((size_t)(b * C + cobase + rr) * H + h) * W + wc] =
                        acc[m][n][rr] + bv[rr];
            } else {
                const size_t nb = ((size_t)(b * H + h) * W + wc) * C + cobase;
                float mm[4];
                if constexpr (MODE == 1) {
#pragma unroll
                    for (int rr = 0; rr < 4; ++rr) {
                        float vv = acc[m][n][rr] + bv[rr];
                        float xv = xf[((size_t)(b * C + cobase + rr) * H + h) * W + wc];
                        mm[rr] = fmaxf(xv, vv);
                    }
                    uint2 um = {(unsigned)f2bf(mm[0]) | ((unsigned)f2bf(mm[1]) << 16),
                                (unsigned)f2bf(mm[2]) | ((unsigned)f2bf(mm[3]) << 16)};
                    *(uint2*)(xmax + nb) = um;
                } else {
                    uint2 mv = *(const uint2*)(xmax + nb);
                    mm[0] = fmaxf(acc[m][n][0] + bv[0], bf2f((ushort)(mv.x & 0xffffu)));
                    mm[1] = fmaxf(acc[m][n][1] + bv[1], bf2f((ushort)(mv.x >> 16)));
                    mm[2] = fmaxf(acc[m][n][2] + bv[2], bf2f((ushort)(mv.y & 0xffffu)));
                    mm[3] = fmaxf(acc[m][n][3] + bv[3], bf2f((ushort)(mv.y >> 16)));
                }
                uint2 px = {(unsigned)f2bf(pm(mm[0], ap)) | ((unsigned)f2bf(pm(mm[1], ap)) << 16),
                            (unsigned)f2bf(pm(mm[2], ap)) | ((unsigned)f2bf(pm(mm[3], ap)) << 16)};
                *(uint2*)(XtOut + nb) = px;
            }
        }
    }
}

// ---------------------------------------------------------------------------
extern "C" void kernel_launch(void* const* d_in, const int* in_sizes, int n_in,
                              void* d_out, int out_size, void* d_ws, size_t ws_size,
                              hipStream_t stream)
{
    const float* x  = (const float*)d_in[0];
    const float* w1 = (const float*)d_in[1];
    const float* b1 = (const float*)d_in[2];
    const float* w2 = (const float*)d_in[3];
    const float* b2 = (const float*)d_in[4];
    const float* w3 = (const float*)d_in[5];
    const float* b3 = (const float*)d_in[6];
    const float* pa = (const float*)d_in[7];

    char* ws = (char*)d_ws;
    ushort* Xt1  = (ushort*)ws;                       // 67108864 B (bf16 NHWC)
    ushort* Xt2  = (ushort*)(ws + 67108864);          // 67108864 B (bf16 NHWC)
    ushort* xmax = (ushort*)(ws + 134217728);         // 67108864 B (bf16 NHWC)
    ushort* Wtf  = (ushort*)(ws + 201326592);         // 3 x 1179648 B

    // opt-in to >64KB dynamic LDS for the conv kernels (once per process)
    static bool attr_done = false;
    if (!attr_done) {
        hipFuncSetAttribute((const void*)conv_kernel<0>,
                            hipFuncAttributeMaxDynamicSharedMemorySize, SA_BYTES);
        hipFuncSetAttribute((const void*)conv_kernel<1>,
                            hipFuncAttributeMaxDynamicSharedMemorySize, SA_BYTES);
        hipFuncSetAttribute((const void*)conv_kernel<2>,
                            hipFuncAttributeMaxDynamicSharedMemorySize, SA_BYTES);
        attr_done = true;
    }

    dim3 tg(4, 128, 8), tb(256);
    dim3 cbk(512);

    wtrans_kernel<<<dim3(256, 1, 3), 256, 0, stream>>>(w1, w2, w3, Wtf);
    // Xt1 = pm(x)  (NHWC bf16)
    xt1_kernel<<<tg, tb, 0, stream>>>(x, pa, Xt1);
    // conv1 + fused max/prelu/mask/transpose: xmax = max(x, conv1), Xt2 = pm(xmax)
    conv_kernel<1><<<dim3(2048), cbk, SA_BYTES, stream>>>(Xt1, Wtf, b1, pa, x, xmax, Xt2, nullptr);
    // conv2 + fused: Xt1 (dead, reused) = pm(max(conv2, xmax))
    conv_kernel<2><<<dim3(2048), cbk, SA_BYTES, stream>>>(Xt2, Wtf + WSZ, b2, pa, nullptr, xmax, Xt1, nullptr);
    // conv3 -> fp32 out
    conv_kernel<0><<<dim3(2048), cbk, SA_BYTES, stream>>>(Xt1, Wtf + 2 * WSZ, b3, pa, nullptr, nullptr, nullptr, (float*)d_out);
}